// Round 5
// baseline (102.598 us; speedup 1.0000x reference)
//
#include <hip/hip_runtime.h>
#include <hip/hip_bf16.h>
#include <math.h>

#define B_ 2
#define C_ 128
#define H_ 56
#define W_ 56
#define N_ (H_*W_)      // 3136
#define HEADS_ 4
#define DH_ 32
#define MW_ 28          // W/2
#define NPOS_ (H_*MW_)  // 1568

typedef unsigned short ushort_t;
typedef __bf16 v8bf __attribute__((ext_vector_type(8)));
typedef float  v4f  __attribute__((ext_vector_type(4)));

#define MFMA16(a,b,c) __builtin_amdgcn_mfma_f32_16x16x32_bf16((a),(b),(c),0,0,0)

__device__ __forceinline__ unsigned short f2bf(float f) {
    return __builtin_bit_cast(unsigned short, __float2bfloat16(f));
}
__device__ __forceinline__ unsigned int bfpack(float a, float b) {
    return (unsigned int)f2bf(a) | ((unsigned int)f2bf(b) << 16);
}
__device__ __forceinline__ void unpack8(uint4 u, float* f) {
    f[0] = __uint_as_float(u.x << 16); f[1] = __uint_as_float(u.x & 0xffff0000u);
    f[2] = __uint_as_float(u.y << 16); f[3] = __uint_as_float(u.y & 0xffff0000u);
    f[4] = __uint_as_float(u.z << 16); f[5] = __uint_as_float(u.z & 0xffff0000u);
    f[6] = __uint_as_float(u.w << 16); f[7] = __uint_as_float(u.w & 0xffff0000u);
}

// ---------------------------------------------------------------------------
// K0: transpose+convert x [b][c][n] f32 -> xbf [b][n][c] bf16.
// 64 px x 128 ch per block via LDS; rotated column reads keep LDS <=2-way.
// ---------------------------------------------------------------------------
__global__ __launch_bounds__(256)
void xpose_kernel(const float* __restrict__ x, ushort_t* __restrict__ xbf) {
    __shared__ float xs[128 * 68];
    const int t  = threadIdx.x;
    const int n0 = blockIdx.x * 64;
    const int b  = blockIdx.y;
    const float* xb = x + (size_t)b * C_ * N_;

    for (int it = 0; it < 8; ++it) {
        int idx = t + it * 256;                  // 128 ch x 16 f4
        int c = idx >> 4, f4 = idx & 15;
        *(float4*)(&xs[c * 68 + f4 * 4]) =
            *(const float4*)(xb + (size_t)c * N_ + n0 + f4 * 4);
    }
    __syncthreads();
    const int rot = t & 7;
    for (int it = 0; it < 4; ++it) {
        int task = t + it * 256;                 // 64 px x 16 ch-groups
        int ug = task & 15, px = task >> 4;
        float f[8];
        #pragma unroll
        for (int s = 0; s < 8; ++s) {
            int u = (s + rot) & 7;
            f[u] = xs[(ug * 8 + u) * 68 + px];
        }
        uint4 o;
        o.x = bfpack(f[0], f[1]); o.y = bfpack(f[2], f[3]);
        o.z = bfpack(f[4], f[5]); o.w = bfpack(f[6], f[7]);
        *(uint4*)(xbf + ((size_t)b * N_ + n0 + px) * C_ + ug * 8) = o;
    }
}

// ---------------------------------------------------------------------------
// K1: fused qkv projections (blockIdx.y 0..5) + asym gate (blockIdx.y == 6).
// Reads xbf (bf16 pixel-major); q/k/v written bf16 pixel-major.
// NOTE: uint4 on ushort_t* covers 8 elements -> all strides are *8.
// ---------------------------------------------------------------------------
__global__ __launch_bounds__(256)
void qkv_asym_kernel(const ushort_t* __restrict__ xbf,
                     const float* __restrict__ Wq, const float* __restrict__ Wk,
                     const float* __restrict__ Wv,
                     const float* __restrict__ Wa1, const float* __restrict__ ba1,
                     const float* __restrict__ Wa2, const float* __restrict__ ba2,
                     ushort_t* __restrict__ q, ushort_t* __restrict__ k,
                     ushort_t* __restrict__ v, float* __restrict__ aval) {
    __shared__ __align__(16) char smem[35840];
    const int t = threadIdx.x;
    const int b = blockIdx.z;
    const int wv_ = t >> 6;
    const int l   = t & 63;
    const int lr  = l & 15;
    const int lq  = l >> 4;

    if (blockIdx.y < 6) {
        // ---------------- q/k/v projection path ----------------
        ushort_t* WT = (ushort_t*)smem;             // [64][136]
        ushort_t* XT = (ushort_t*)(smem + 17408);   // [64][136]

        const int n0   = blockIdx.x * 64;
        const int mIdx = blockIdx.y >> 1;
        const int o0   = (blockIdx.y & 1) * 64;
        const float* W  = (mIdx == 0 ? Wq : (mIdx == 1 ? Wk : Wv));
        ushort_t* dst   = (mIdx == 0 ? q  : (mIdx == 1 ? k  : v ));

        for (int it = 0; it < 8; ++it) {
            int idx = t + it * 256;                 // 64 rows x 32 ushort4
            int row = idx >> 5, f4 = idx & 31;
            float4 w4 = *(const float4*)(W + (size_t)(o0 + row) * C_ + f4 * 4);
            ushort4 p4 = { f2bf(w4.x), f2bf(w4.y), f2bf(w4.z), f2bf(w4.w) };
            *(ushort4*)(WT + row * 136 + f4 * 4) = p4;
        }
        for (int it = 0; it < 4; ++it) {
            int idx = t + it * 256;                 // 64 px x 16 uint4 (8 ch each)
            int px = idx >> 4, g = idx & 15;
            uint4 r = *(const uint4*)(xbf + ((size_t)b * N_ + n0 + px) * C_ + g * 8);
            *(uint4*)(XT + px * 136 + g * 8) = r;
        }
        __syncthreads();

        v4f acc[4];
        #pragma unroll
        for (int nt = 0; nt < 4; ++nt) acc[nt] = (v4f){0.f, 0.f, 0.f, 0.f};

        #pragma unroll
        for (int ks = 0; ks < 4; ++ks) {
            v8bf af = *(const v8bf*)(WT + (wv_ * 16 + lr) * 136 + ks * 32 + lq * 8);
            #pragma unroll
            for (int nt = 0; nt < 4; ++nt) {
                v8bf bfr = *(const v8bf*)(XT + (nt * 16 + lr) * 136 + ks * 32 + lq * 8);
                acc[nt] = MFMA16(af, bfr, acc[nt]);
            }
        }

        // epilogue: bf16 transpose via LDS (reuse WT), coalesced 16B stores
        __syncthreads();
        ushort_t* epT = WT;                          // [64 px][136]
        #pragma unroll
        for (int nt = 0; nt < 4; ++nt) {
            uint2 pk;
            pk.x = bfpack(acc[nt][0], acc[nt][1]);
            pk.y = bfpack(acc[nt][2], acc[nt][3]);
            *(uint2*)(epT + (nt * 16 + lr) * 136 + wv_ * 16 + lq * 4) = pk;
        }
        __syncthreads();
        for (int it = 0; it < 2; ++it) {
            int idx = t + it * 256;                  // 64 px x 8 uint4 (64 ch)
            int px = idx >> 3, g = idx & 7;
            *(uint4*)(dst + ((size_t)b * N_ + n0 + px) * C_ + o0 + g * 8) =
                *(const uint4*)(epT + px * 136 + g * 8);
        }
    } else {
        // ---------------- asym gate path ----------------
        ushort_t* wa  = (ushort_t*)smem;             // [128][72]
        ushort_t* cat = (ushort_t*)(smem + 18432);   // [32][264]
        float* wred   = (float*)(smem + 35328);      // [4][32]

        const int P0 = blockIdx.x * 32;              // 49*32 = 1568

        // stage cat = [left(128) ; flip(right)(128)] bf16 [pos][ch]
        for (int it = 0; it < 4; ++it) {
            int idx = t + it * 256;                  // 32 pos x 32 uint4
            int pos = idx >> 5, g = idx & 31;
            int pg = P0 + pos;
            int h = pg / MW_, j = pg - h * MW_;
            int n = h * W_ + ((g < 16) ? j : (W_ - 1 - j));
            uint4 r = *(const uint4*)(xbf + ((size_t)b * N_ + n) * C_ + (g & 15) * 8);
            *(uint4*)(cat + pos * 264 + g * 8) = r;
        }

        v4f acc2[2][2];
        #pragma unroll
        for (int mi = 0; mi < 2; ++mi)
            #pragma unroll
            for (int nt = 0; nt < 2; ++nt) acc2[mi][nt] = (v4f){0.f, 0.f, 0.f, 0.f};

        for (int kc = 0; kc < 4; ++kc) {
            __syncthreads();     // also covers initial cat staging (kc==0)
            for (int it = 0; it < 8; ++it) {
                int idx = t + it * 256;              // 128 rows x 16 ushort4
                int row = idx >> 4, f4 = idx & 15;
                float4 w4 = *(const float4*)(Wa1 + (size_t)row * 256 + kc * 64 + f4 * 4);
                ushort4 p4 = { f2bf(w4.x), f2bf(w4.y), f2bf(w4.z), f2bf(w4.w) };
                *(ushort4*)(wa + row * 72 + f4 * 4) = p4;
            }
            __syncthreads();
            #pragma unroll
            for (int ks = 0; ks < 2; ++ks) {
                v8bf a0f = *(const v8bf*)(wa + ((2*wv_ + 0) * 16 + lr) * 72 + ks * 32 + lq * 8);
                v8bf a1f = *(const v8bf*)(wa + ((2*wv_ + 1) * 16 + lr) * 72 + ks * 32 + lq * 8);
                v8bf b0f = *(const v8bf*)(cat + lr * 264        + kc * 64 + ks * 32 + lq * 8);
                v8bf b1f = *(const v8bf*)(cat + (16 + lr) * 264 + kc * 64 + ks * 32 + lq * 8);
                acc2[0][0] = MFMA16(a0f, b0f, acc2[0][0]);
                acc2[0][1] = MFMA16(a0f, b1f, acc2[0][1]);
                acc2[1][0] = MFMA16(a1f, b0f, acc2[1][0]);
                acc2[1][1] = MFMA16(a1f, b1f, acc2[1][1]);
            }
        }

        float p2[2] = {0.f, 0.f};
        #pragma unroll
        for (int mi = 0; mi < 2; ++mi) {
            #pragma unroll
            for (int r = 0; r < 4; ++r) {
                int m = (2*wv_ + mi) * 16 + lq * 4 + r;
                float wa2v = Wa2[m];
                float b1v  = ba1[m];
                #pragma unroll
                for (int nt = 0; nt < 2; ++nt) {
                    float val = acc2[mi][nt][r] + b1v;
                    float gl = 0.5f * val * (1.0f + erff(val * 0.7071067811865475f));
                    p2[nt] += gl * wa2v;
                }
            }
        }
        #pragma unroll
        for (int nt = 0; nt < 2; ++nt) {
            p2[nt] += __shfl_xor(p2[nt], 16, 64);
            p2[nt] += __shfl_xor(p2[nt], 32, 64);
        }
        if (l < 16) {
            wred[wv_ * 32 + lr]      = p2[0];
            wred[wv_ * 32 + 16 + lr] = p2[1];
        }
        __syncthreads();
        if (t < 32) {
            float s = wred[t] + wred[32 + t] + wred[64 + t] + wred[96 + t] + ba2[0];
            aval[(size_t)b * NPOS_ + P0 + t] = 1.0f / (1.0f + expf(-s));
        }
    }
}

// ---------------------------------------------------------------------------
// K2: fused 3x3 neighborhood attention (+asym gate) -> LDS bf16 -> oproj MFMA.
// 32-px tile per block; attn = 512 tasks (2/thread), q/k/v bf16 in global.
// ---------------------------------------------------------------------------
__global__ __launch_bounds__(256)
void attn_oproj_kernel(const ushort_t* __restrict__ q, const ushort_t* __restrict__ k,
                       const ushort_t* __restrict__ v, const float* __restrict__ aval,
                       const float* __restrict__ Wo, const float* __restrict__ bo,
                       float* __restrict__ out) {
    __shared__ __align__(16) char smem[53248];
    ushort_t* WoT = (ushort_t*)smem;                 // [128][136]
    ushort_t* aoT = (ushort_t*)(smem + 34816);       // [32][136]
    float*    ep  = (float*)(smem + 34816);          // [128][36] (aliases aoT)

    const int t  = threadIdx.x;
    const int n0 = blockIdx.x * 32;
    const int b  = blockIdx.y;

    // stage Wo -> bf16 LDS: 128 rows x 32 ushort4 = 4096 tasks
    for (int it = 0; it < 16; ++it) {
        int idx = t + it * 256;
        int row = idx >> 5, f4 = idx & 31;
        float4 w4 = *(const float4*)(Wo + (size_t)row * C_ + f4 * 4);
        ushort4 p4 = { f2bf(w4.x), f2bf(w4.y), f2bf(w4.z), f2bf(w4.w) };
        *(ushort4*)(WoT + row * 136 + f4 * 4) = p4;
    }

    // attention: 32 px x 4 heads x 4 dim-slices = 512 tasks
    const size_t base = (size_t)b * N_ * C_;
    for (int u = 0; u < 2; ++u) {
        int task = t + u * 256;
        int s = task & 3, head = (task >> 2) & 3, p = task >> 4;
        int n = n0 + p;
        int i = n / W_, j = n - i * W_;
        int dbase = head * DH_ + s * 8;

        float qf[8];
        unpack8(*(const uint4*)(q + base + (size_t)n * C_ + dbase), qf);

        float dts[9]; int mm[9];
        #pragma unroll
        for (int tt = 0; tt < 9; ++tt) {
            int di = tt / 3 - 1, dj = tt % 3 - 1;
            int ii = i + di, jj = j + dj;
            bool ok = ((unsigned)ii < (unsigned)H_) && ((unsigned)jj < (unsigned)W_);
            int m = ok ? ii * W_ + jj : n;
            mm[tt] = m;
            float kf[8];
            unpack8(*(const uint4*)(k + base + (size_t)m * C_ + dbase), kf);
            float pd = qf[0]*kf[0] + qf[1]*kf[1] + qf[2]*kf[2] + qf[3]*kf[3]
                     + qf[4]*kf[4] + qf[5]*kf[5] + qf[6]*kf[6] + qf[7]*kf[7];
            pd += __shfl_xor(pd, 1, 64);
            pd += __shfl_xor(pd, 2, 64);
            dts[tt] = ok ? pd * 0.17677669529663687f : -1e30f;
        }
        float mx = dts[0];
        #pragma unroll
        for (int tt = 1; tt < 9; ++tt) mx = fmaxf(mx, dts[tt]);
        float sum = 0.f;
        #pragma unroll
        for (int tt = 0; tt < 9; ++tt) { dts[tt] = expf(dts[tt] - mx); sum += dts[tt]; }
        const float inv = 1.0f / sum;

        float acc[8] = {0,0,0,0,0,0,0,0};
        #pragma unroll
        for (int tt = 0; tt < 9; ++tt) {
            float vf[8];
            unpack8(*(const uint4*)(v + base + (size_t)mm[tt] * C_ + dbase), vf);
            float wt = dts[tt] * inv;
            #pragma unroll
            for (int d = 0; d < 8; ++d) acc[d] += wt * vf[d];
        }

        // asym: linear 28->56 along width (half-pixel centers, clamped edges)
        float f = 0.5f * (float)j - 0.25f;
        f = fminf(fmaxf(f, 0.0f), 27.0f);
        int i0 = (int)f; if (i0 > 26) i0 = 26;
        float frac = f - (float)i0;
        const float* av = aval + (size_t)b * NPOS_ + i * MW_;
        float a = av[i0] * (1.0f - frac) + av[i0 + 1] * frac;
        float sc = 1.0f + 0.5f * a;

        uint4 o;
        o.x = bfpack(acc[0] * sc, acc[1] * sc);
        o.y = bfpack(acc[2] * sc, acc[3] * sc);
        o.z = bfpack(acc[4] * sc, acc[5] * sc);
        o.w = bfpack(acc[6] * sc, acc[7] * sc);
        *(uint4*)(aoT + p * 136 + dbase) = o;
    }
    __syncthreads();

    // oproj MFMA: wave w -> m-tiles {2w,2w+1} x n-tiles {0,1}, K=128
    const int wv_ = t >> 6, l = t & 63, lr = l & 15, lq = l >> 4;
    v4f acc4[2][2];
    #pragma unroll
    for (int mi = 0; mi < 2; ++mi)
        #pragma unroll
        for (int nt = 0; nt < 2; ++nt) acc4[mi][nt] = (v4f){0.f, 0.f, 0.f, 0.f};

    #pragma unroll
    for (int ks = 0; ks < 4; ++ks) {
        v8bf b0 = *(const v8bf*)(aoT + lr * 136        + ks * 32 + lq * 8);
        v8bf b1 = *(const v8bf*)(aoT + (16 + lr) * 136 + ks * 32 + lq * 8);
        #pragma unroll
        for (int mi = 0; mi < 2; ++mi) {
            v8bf af = *(const v8bf*)(WoT + ((wv_ * 2 + mi) * 16 + lr) * 136 + ks * 32 + lq * 8);
            acc4[mi][0] = MFMA16(af, b0, acc4[mi][0]);
            acc4[mi][1] = MFMA16(af, b1, acc4[mi][1]);
        }
    }
    __syncthreads();    // aoT reads done; ep aliases that region

    #pragma unroll
    for (int mi = 0; mi < 2; ++mi) {
        int o = (wv_ * 2 + mi) * 16 + lq * 4;
        float4 bv = *(const float4*)(bo + o);
        const float bvr[4] = { bv.x, bv.y, bv.z, bv.w };
        #pragma unroll
        for (int nt = 0; nt < 2; ++nt)
            #pragma unroll
            for (int r = 0; r < 4; ++r)
                ep[(o + r) * 36 + nt * 16 + lr] = acc4[mi][nt][r] + bvr[r];
    }
    __syncthreads();
    for (int it = 0; it < 4; ++it) {
        int idx = t + it * 256;                      // 128 o x 8 f4
        int o = idx >> 3, f4 = idx & 7;
        *(float4*)(out + (size_t)b * C_ * N_ + (size_t)o * N_ + n0 + f4 * 4) =
            *(const float4*)(ep + o * 36 + f4 * 4);
    }
}

// ---------------------------------------------------------------------------
extern "C" void kernel_launch(void* const* d_in, const int* in_sizes, int n_in,
                              void* d_out, int out_size, void* d_ws, size_t ws_size,
                              hipStream_t stream) {
    const float* x   = (const float*)d_in[0];
    const float* Wq  = (const float*)d_in[1];
    const float* Wk  = (const float*)d_in[2];
    const float* Wv  = (const float*)d_in[3];
    const float* Wo  = (const float*)d_in[4];
    const float* bo  = (const float*)d_in[5];
    const float* Wa1 = (const float*)d_in[6];
    const float* ba1 = (const float*)d_in[7];
    const float* Wa2 = (const float*)d_in[8];
    const float* ba2 = (const float*)d_in[9];
    float* out = (float*)d_out;

    const size_t PXC = (size_t)B_ * N_ * C_;   // 802816
    ushort_t* qb  = (ushort_t*)d_ws;
    ushort_t* kb  = qb + PXC;
    ushort_t* vb  = kb + PXC;
    ushort_t* xbf = vb + PXC;
    float*    aval = (float*)(xbf + PXC);      // B*NPOS_ floats

    xpose_kernel   <<<dim3(49, B_), 256, 0, stream>>>(x, xbf);
    qkv_asym_kernel<<<dim3(49, 7, B_), 256, 0, stream>>>(
        xbf, Wq, Wk, Wv, Wa1, ba1, Wa2, ba2, qb, kb, vb, aval);
    attn_oproj_kernel<<<dim3(98, B_), 256, 0, stream>>>(qb, kb, vb, aval, Wo, bo, out);
}

// Round 6
// 89.344 us; speedup vs baseline: 1.1483x; 1.1483x over previous
//
#include <hip/hip_runtime.h>
#include <hip/hip_bf16.h>
#include <math.h>

#define B_ 2
#define C_ 128
#define H_ 56
#define W_ 56
#define N_ (H_*W_)      // 3136
#define HEADS_ 4
#define DH_ 32
#define MW_ 28          // W/2
#define NPOS_ (H_*MW_)  // 1568

typedef unsigned short ushort_t;
typedef __bf16 v8bf __attribute__((ext_vector_type(8)));
typedef float  v4f  __attribute__((ext_vector_type(4)));

#define MFMA16(a,b,c) __builtin_amdgcn_mfma_f32_16x16x32_bf16((a),(b),(c),0,0,0)

__device__ __forceinline__ unsigned short f2bf(float f) {
    return __builtin_bit_cast(unsigned short, __float2bfloat16(f));
}
__device__ __forceinline__ unsigned int bfpack(float a, float b) {
    return (unsigned int)f2bf(a) | ((unsigned int)f2bf(b) << 16);
}
__device__ __forceinline__ void unpack8(uint4 u, float* f) {
    f[0] = __uint_as_float(u.x << 16); f[1] = __uint_as_float(u.x & 0xffff0000u);
    f[2] = __uint_as_float(u.y << 16); f[3] = __uint_as_float(u.y & 0xffff0000u);
    f[4] = __uint_as_float(u.z << 16); f[5] = __uint_as_float(u.z & 0xffff0000u);
    f[6] = __uint_as_float(u.w << 16); f[7] = __uint_as_float(u.w & 0xffff0000u);
}

// ---------------------------------------------------------------------------
// K1: fused qkv projections (blockIdx.y 0..5) + asym gate (blockIdx.y == 6).
// Stages x (fp32 channel-major) per block; q/k/v written bf16 pixel-major.
// ---------------------------------------------------------------------------
__global__ __launch_bounds__(256)
void qkv_asym_kernel(const float* __restrict__ x,
                     const float* __restrict__ Wq, const float* __restrict__ Wk,
                     const float* __restrict__ Wv,
                     const float* __restrict__ Wa1, const float* __restrict__ ba1,
                     const float* __restrict__ Wa2, const float* __restrict__ ba2,
                     ushort_t* __restrict__ q, ushort_t* __restrict__ k,
                     ushort_t* __restrict__ v, float* __restrict__ aval) {
    __shared__ __align__(16) char smem[35840];
    const int t = threadIdx.x;
    const int b = blockIdx.z;
    const int wv_ = t >> 6;
    const int l   = t & 63;
    const int lr  = l & 15;
    const int lq  = l >> 4;

    if (blockIdx.y < 6) {
        // ---------------- q/k/v projection path ----------------
        ushort_t* WT = (ushort_t*)smem;             // [64][136]
        ushort_t* XT = (ushort_t*)(smem + 17408);   // [64][136]

        const int n0   = blockIdx.x * 64;
        const int mIdx = blockIdx.y >> 1;
        const int o0   = (blockIdx.y & 1) * 64;
        const float* W  = (mIdx == 0 ? Wq : (mIdx == 1 ? Wk : Wv));
        ushort_t* dst   = (mIdx == 0 ? q  : (mIdx == 1 ? k  : v ));
        const float* xb = x + (size_t)b * C_ * N_;

        // stage W tile: 64 rows x 32 ushort4, coalesced
        for (int it = 0; it < 8; ++it) {
            int idx = t + it * 256;
            int row = idx >> 5, f4 = idx & 31;
            float4 w4 = *(const float4*)(W + (size_t)(o0 + row) * C_ + f4 * 4);
            ushort4 p4 = { f2bf(w4.x), f2bf(w4.y), f2bf(w4.z), f2bf(w4.w) };
            *(ushort4*)(WT + row * 136 + f4 * 4) = p4;
        }
        // stage X^T tile: lane = pixel (coalesced per channel), 32 ch/thread
        {
            int px = t & 63, g = t >> 6;
            const float* xc = xb + n0 + px;
            for (int it = 0; it < 8; ++it) {
                int c0 = (g + it * 4) * 4;          // channel quad base
                float a0 = xc[(size_t)(c0 + 0) * N_];
                float a1 = xc[(size_t)(c0 + 1) * N_];
                float a2 = xc[(size_t)(c0 + 2) * N_];
                float a3 = xc[(size_t)(c0 + 3) * N_];
                ushort4 p4 = { f2bf(a0), f2bf(a1), f2bf(a2), f2bf(a3) };
                *(ushort4*)(XT + px * 136 + c0) = p4;
            }
        }
        __syncthreads();

        v4f acc[4];
        #pragma unroll
        for (int nt = 0; nt < 4; ++nt) acc[nt] = (v4f){0.f, 0.f, 0.f, 0.f};

        #pragma unroll
        for (int ks = 0; ks < 4; ++ks) {
            v8bf af = *(const v8bf*)(WT + (wv_ * 16 + lr) * 136 + ks * 32 + lq * 8);
            #pragma unroll
            for (int nt = 0; nt < 4; ++nt) {
                v8bf bfr = *(const v8bf*)(XT + (nt * 16 + lr) * 136 + ks * 32 + lq * 8);
                acc[nt] = MFMA16(af, bfr, acc[nt]);
            }
        }

        // epilogue: bf16 transpose via LDS (reuse WT), coalesced 16B stores
        __syncthreads();
        ushort_t* epT = WT;                          // [64 px][136]
        #pragma unroll
        for (int nt = 0; nt < 4; ++nt) {
            uint2 pk;
            pk.x = bfpack(acc[nt][0], acc[nt][1]);
            pk.y = bfpack(acc[nt][2], acc[nt][3]);
            *(uint2*)(epT + (nt * 16 + lr) * 136 + wv_ * 16 + lq * 4) = pk;
        }
        __syncthreads();
        for (int it = 0; it < 2; ++it) {
            int idx = t + it * 256;                  // 64 px x 8 uint4 (64 ch)
            int px = idx >> 3, g = idx & 7;
            *(uint4*)(dst + ((size_t)b * N_ + n0 + px) * C_ + o0 + g * 8) =
                *(const uint4*)(epT + px * 136 + g * 8);
        }
    } else {
        // ---------------- asym gate path ----------------
        ushort_t* wa  = (ushort_t*)smem;             // [128][72]
        ushort_t* cat = (ushort_t*)(smem + 18432);   // [32][264]
        float* wred   = (float*)(smem + 35328);      // [4][32]

        const int P0 = blockIdx.x * 32;              // 49*32 = 1568
        const float* xb = x + (size_t)b * C_ * N_;

        // stage cat = [left(128) ; flip(right)(128)] bf16 [pos][ch]
        {
            int pos = t & 31, chg = t >> 5;          // chg 0..7
            int pg = P0 + pos;
            int h = pg / MW_, j = pg - h * MW_;
            int col = (chg < 4) ? (h * W_ + j) : (h * W_ + (W_ - 1 - j));
            int cbase = (chg & 3) * 32;
            const float* src = xb + col;
            ushort_t* crow = cat + pos * 264 + chg * 32;
            #pragma unroll
            for (int u = 0; u < 16; ++u) {
                float f0 = src[(size_t)(cbase + 2 * u) * N_];
                float f1 = src[(size_t)(cbase + 2 * u + 1) * N_];
                ushort2 pp = { f2bf(f0), f2bf(f1) };
                *(ushort2*)(crow + 2 * u) = pp;
            }
        }

        v4f acc2[2][2];
        #pragma unroll
        for (int mi = 0; mi < 2; ++mi)
            #pragma unroll
            for (int nt = 0; nt < 2; ++nt) acc2[mi][nt] = (v4f){0.f, 0.f, 0.f, 0.f};

        for (int kc = 0; kc < 4; ++kc) {
            __syncthreads();     // also covers initial cat staging (kc==0)
            for (int it = 0; it < 8; ++it) {
                int idx = t + it * 256;              // 128 rows x 16 ushort4
                int row = idx >> 4, f4 = idx & 15;
                float4 w4 = *(const float4*)(Wa1 + (size_t)row * 256 + kc * 64 + f4 * 4);
                ushort4 p4 = { f2bf(w4.x), f2bf(w4.y), f2bf(w4.z), f2bf(w4.w) };
                *(ushort4*)(wa + row * 72 + f4 * 4) = p4;
            }
            __syncthreads();
            #pragma unroll
            for (int ks = 0; ks < 2; ++ks) {
                v8bf a0f = *(const v8bf*)(wa + ((2*wv_ + 0) * 16 + lr) * 72 + ks * 32 + lq * 8);
                v8bf a1f = *(const v8bf*)(wa + ((2*wv_ + 1) * 16 + lr) * 72 + ks * 32 + lq * 8);
                v8bf b0f = *(const v8bf*)(cat + lr * 264        + kc * 64 + ks * 32 + lq * 8);
                v8bf b1f = *(const v8bf*)(cat + (16 + lr) * 264 + kc * 64 + ks * 32 + lq * 8);
                acc2[0][0] = MFMA16(a0f, b0f, acc2[0][0]);
                acc2[0][1] = MFMA16(a0f, b1f, acc2[0][1]);
                acc2[1][0] = MFMA16(a1f, b0f, acc2[1][0]);
                acc2[1][1] = MFMA16(a1f, b1f, acc2[1][1]);
            }
        }

        float p2[2] = {0.f, 0.f};
        #pragma unroll
        for (int mi = 0; mi < 2; ++mi) {
            #pragma unroll
            for (int r = 0; r < 4; ++r) {
                int m = (2*wv_ + mi) * 16 + lq * 4 + r;
                float wa2v = Wa2[m];
                float b1v  = ba1[m];
                #pragma unroll
                for (int nt = 0; nt < 2; ++nt) {
                    float val = acc2[mi][nt][r] + b1v;
                    float gl = 0.5f * val * (1.0f + erff(val * 0.7071067811865475f));
                    p2[nt] += gl * wa2v;
                }
            }
        }
        #pragma unroll
        for (int nt = 0; nt < 2; ++nt) {
            p2[nt] += __shfl_xor(p2[nt], 16, 64);
            p2[nt] += __shfl_xor(p2[nt], 32, 64);
        }
        if (l < 16) {
            wred[wv_ * 32 + lr]      = p2[0];
            wred[wv_ * 32 + 16 + lr] = p2[1];
        }
        __syncthreads();
        if (t < 32) {
            float s = wred[t] + wred[32 + t] + wred[64 + t] + wred[96 + t] + ba2[0];
            aval[(size_t)b * NPOS_ + P0 + t] = 1.0f / (1.0f + expf(-s));
        }
    }
}

// ---------------------------------------------------------------------------
// K2: fused 3x3 neighborhood attention (+asym gate) -> LDS bf16 -> oproj MFMA.
// 16-px tile per block (392 blocks): exactly ONE attn task per thread.
// ---------------------------------------------------------------------------
__global__ __launch_bounds__(256)
void attn_oproj_kernel(const ushort_t* __restrict__ q, const ushort_t* __restrict__ k,
                       const ushort_t* __restrict__ v, const float* __restrict__ aval,
                       const float* __restrict__ Wo, const float* __restrict__ bo,
                       float* __restrict__ out) {
    __shared__ __align__(16) char smem[45056];
    ushort_t* WoT = (ushort_t*)smem;                 // [128][136]
    ushort_t* aoT = (ushort_t*)(smem + 34816);       // [16][136]
    float*    ep  = (float*)(smem + 34816);          // [128][20] (aliases aoT)

    const int t  = threadIdx.x;
    const int n0 = blockIdx.x * 16;
    const int b  = blockIdx.y;

    // stage Wo -> bf16 LDS: 128 rows x 32 ushort4 (independent of attn loads)
    for (int it = 0; it < 16; ++it) {
        int idx = t + it * 256;
        int row = idx >> 5, f4 = idx & 31;
        float4 w4 = *(const float4*)(Wo + (size_t)row * C_ + f4 * 4);
        ushort4 p4 = { f2bf(w4.x), f2bf(w4.y), f2bf(w4.z), f2bf(w4.w) };
        *(ushort4*)(WoT + row * 136 + f4 * 4) = p4;
    }

    // attention: 16 px x 4 heads x 4 dim-slices = 256 tasks, 1/thread
    const size_t base = (size_t)b * N_ * C_;
    {
        int s = t & 3, head = (t >> 2) & 3, p = t >> 4;
        int n = n0 + p;
        int i = n / W_, j = n - i * W_;
        int dbase = head * DH_ + s * 8;

        float qf[8];
        unpack8(*(const uint4*)(q + base + (size_t)n * C_ + dbase), qf);

        float dts[9]; int mm[9];
        #pragma unroll
        for (int tt = 0; tt < 9; ++tt) {
            int di = tt / 3 - 1, dj = tt % 3 - 1;
            int ii = i + di, jj = j + dj;
            bool ok = ((unsigned)ii < (unsigned)H_) && ((unsigned)jj < (unsigned)W_);
            int m = ok ? ii * W_ + jj : n;
            mm[tt] = m;
            float kf[8];
            unpack8(*(const uint4*)(k + base + (size_t)m * C_ + dbase), kf);
            float pd = qf[0]*kf[0] + qf[1]*kf[1] + qf[2]*kf[2] + qf[3]*kf[3]
                     + qf[4]*kf[4] + qf[5]*kf[5] + qf[6]*kf[6] + qf[7]*kf[7];
            pd += __shfl_xor(pd, 1, 64);
            pd += __shfl_xor(pd, 2, 64);
            dts[tt] = ok ? pd * 0.17677669529663687f : -1e30f;  // 1/sqrt(32)
        }
        float mx = dts[0];
        #pragma unroll
        for (int tt = 1; tt < 9; ++tt) mx = fmaxf(mx, dts[tt]);
        float sum = 0.f;
        #pragma unroll
        for (int tt = 0; tt < 9; ++tt) { dts[tt] = expf(dts[tt] - mx); sum += dts[tt]; }
        const float inv = 1.0f / sum;

        float acc[8] = {0,0,0,0,0,0,0,0};
        #pragma unroll
        for (int tt = 0; tt < 9; ++tt) {
            float vf[8];
            unpack8(*(const uint4*)(v + base + (size_t)mm[tt] * C_ + dbase), vf);
            float wt = dts[tt] * inv;
            #pragma unroll
            for (int d = 0; d < 8; ++d) acc[d] += wt * vf[d];
        }

        // asym: linear 28->56 along width (half-pixel centers, clamped edges)
        float f = 0.5f * (float)j - 0.25f;
        f = fminf(fmaxf(f, 0.0f), 27.0f);
        int i0 = (int)f; if (i0 > 26) i0 = 26;
        float frac = f - (float)i0;
        const float* av = aval + (size_t)b * NPOS_ + i * MW_;
        float a = av[i0] * (1.0f - frac) + av[i0 + 1] * frac;
        float sc = 1.0f + 0.5f * a;

        uint4 o;
        o.x = bfpack(acc[0] * sc, acc[1] * sc);
        o.y = bfpack(acc[2] * sc, acc[3] * sc);
        o.z = bfpack(acc[4] * sc, acc[5] * sc);
        o.w = bfpack(acc[6] * sc, acc[7] * sc);
        *(uint4*)(aoT + p * 136 + dbase) = o;
    }
    __syncthreads();

    // oproj MFMA: wave w -> m-tiles {2w,2w+1}, single 16-px n-tile, K=128
    const int wv_ = t >> 6, l = t & 63, lr = l & 15, lq = l >> 4;
    v4f acc4[2];
    acc4[0] = (v4f){0.f, 0.f, 0.f, 0.f};
    acc4[1] = (v4f){0.f, 0.f, 0.f, 0.f};

    #pragma unroll
    for (int ks = 0; ks < 4; ++ks) {
        v8bf b0 = *(const v8bf*)(aoT + lr * 136 + ks * 32 + lq * 8);
        #pragma unroll
        for (int mi = 0; mi < 2; ++mi) {
            v8bf af = *(const v8bf*)(WoT + ((wv_ * 2 + mi) * 16 + lr) * 136 + ks * 32 + lq * 8);
            acc4[mi] = MFMA16(af, b0, acc4[mi]);
        }
    }
    __syncthreads();    // aoT reads done; ep aliases that region

    #pragma unroll
    for (int mi = 0; mi < 2; ++mi) {
        int o = (wv_ * 2 + mi) * 16 + lq * 4;
        float4 bv = *(const float4*)(bo + o);
        const float bvr[4] = { bv.x, bv.y, bv.z, bv.w };
        #pragma unroll
        for (int r = 0; r < 4; ++r)
            ep[(o + r) * 20 + lr] = acc4[mi][r] + bvr[r];
    }
    __syncthreads();
    for (int it = 0; it < 2; ++it) {
        int idx = t + it * 256;                      // 128 o x 4 f4
        int o = idx >> 2, f4 = idx & 3;
        *(float4*)(out + (size_t)b * C_ * N_ + (size_t)o * N_ + n0 + f4 * 4) =
            *(const float4*)(ep + o * 20 + f4 * 4);
    }
}

// ---------------------------------------------------------------------------
extern "C" void kernel_launch(void* const* d_in, const int* in_sizes, int n_in,
                              void* d_out, int out_size, void* d_ws, size_t ws_size,
                              hipStream_t stream) {
    const float* x   = (const float*)d_in[0];
    const float* Wq  = (const float*)d_in[1];
    const float* Wk  = (const float*)d_in[2];
    const float* Wv  = (const float*)d_in[3];
    const float* Wo  = (const float*)d_in[4];
    const float* bo  = (const float*)d_in[5];
    const float* Wa1 = (const float*)d_in[6];
    const float* ba1 = (const float*)d_in[7];
    const float* Wa2 = (const float*)d_in[8];
    const float* ba2 = (const float*)d_in[9];
    float* out = (float*)d_out;

    const size_t PXC = (size_t)B_ * N_ * C_;   // 802816
    ushort_t* qb  = (ushort_t*)d_ws;
    ushort_t* kb  = qb + PXC;
    ushort_t* vb  = kb + PXC;
    float*    aval = (float*)(vb + PXC);       // B*NPOS_ floats

    qkv_asym_kernel<<<dim3(49, 7, B_), 256, 0, stream>>>(
        x, Wq, Wk, Wv, Wa1, ba1, Wa2, ba2, qb, kb, vb, aval);
    attn_oproj_kernel<<<dim3(196, B_), 256, 0, stream>>>(qb, kb, vb, aval, Wo, bo, out);
}